// Round 3
// baseline (18.948 us; speedup 1.0000x reference)
//
#include <hip/hip_runtime.h>
#include <hip/hip_bf16.h>
#include <stdint.h>

#define BLOCK 256
#define NBLK  512   // partials: NBLK*5 doubles = 20480 B of d_ws

// Channel constant: NOISE_RATE from the reference (kop is a deterministic
// function of it; hardcoded to avoid any device-dtype ambiguity).
#define G_NOISE 0.233

// ---- order-8 Gauss-Legendre nodes/weights mapped to [0,1] (exact leggauss(8)/2) ----
#define GL_T0 0.019855071751231856
#define GL_T1 0.10166676129318663
#define GL_T2 0.23723379504183550
#define GL_T3 0.40828267875217510
#define GL_T4 0.59171732124782490
#define GL_T5 0.76276620495816449
#define GL_T6 0.89833323870681337
#define GL_T7 0.98014492824876811
#define GL_W0 0.05061426814518813
#define GL_W1 0.11119051722668723
#define GL_W2 0.15685332293894364
#define GL_W3 0.18134107081135099

// F(lam) = lam * glog(lam), glog = 2^6 * sum_j w_j * x / (1 + t_j x),
// x = lam^(1/64) - 1. Reproduces psd_logm's scalar action exactly
// (6 sqrtms + order-8 Gauss-Legendre Pade), applied per eigenvalue.
__device__ __forceinline__ float F_pade_f(float lam) {
    if (!(lam > 0.0f)) return 0.0f;
    const float TJ[8] = {(float)GL_T0,(float)GL_T1,(float)GL_T2,(float)GL_T3,
                         (float)GL_T4,(float)GL_T5,(float)GL_T6,(float)GL_T7};
    const float WJ[8] = {(float)GL_W0,(float)GL_W1,(float)GL_W2,(float)GL_W3,
                         (float)GL_W3,(float)GL_W2,(float)GL_W1,(float)GL_W0};
    float x = expm1f(logf(lam) * 0.015625f);   // lam^(1/64) - 1
    float s = 0.0f;
#pragma unroll
    for (int j = 0; j < 8; ++j)
        s += __fdividef(WJ[j] * x, fmaf(TJ[j], x, 1.0f));
    return 64.0f * lam * s;
}

__device__ __forceinline__ double F_pade_d(double lam) {
    if (!(lam > 0.0)) return 0.0;
    const double TJ[8] = {GL_T0,GL_T1,GL_T2,GL_T3,GL_T4,GL_T5,GL_T6,GL_T7};
    const double WJ[8] = {GL_W0,GL_W1,GL_W2,GL_W3,GL_W3,GL_W2,GL_W1,GL_W0};
    double x = expm1(log(lam) * 0.015625);
    double s = 0.0;
#pragma unroll
    for (int j = 0; j < 8; ++j)
        s += WJ[j] * x / fma(TJ[j], x, 1.0);
    return 64.0 * lam * s;
}

// entropy of a trace-1 Hermitian PSD 2x2 with determinant `det`:
// lam+- = 0.5 +- sqrt(0.25 - det); lam- = det/lam+ (stable for tiny det)
__device__ __forceinline__ float entropy_from_det_f(float det) {
    float disc = 0.25f - det;
    disc = disc > 0.0f ? sqrtf(disc) : 0.0f;
    float lp = 0.5f + disc;
    float lm = __fdividef(det, lp);
    return -(F_pade_f(lp) + F_pade_f(lm));
}

__global__ __launch_bounds__(BLOCK) void reduce_kernel(
    const float* __restrict__ coeff, const float4* __restrict__ state,
    double* __restrict__ partial, int N)
{
    // sigma_n (amplitude damping, per pure state): trace 1, det = g(1-g)*q^2
    const float gg = (float)(G_NOISE * (1.0 - G_NOISE));   // g*(1-g)

    double acc0 = 0.0, acc1 = 0.0, acc2 = 0.0, acc3 = 0.0, acc4 = 0.0;
    const int stride = gridDim.x * blockDim.x;
    for (int i = blockIdx.x * blockDim.x + threadIdx.x; i < N; i += stride) {
        float c = coeff[i];
        float4 s = state[i];                      // Re(psi0), Im(psi0), Re(psi1), Im(psi1)
        float t = log1pf(__expf(c));              // softplus
        float n2 = fmaf(s.x, s.x, fmaf(s.y, s.y, fmaf(s.z, s.z, s.w * s.w)));
        float inv = __fdividef(1.0f, n2);
        float q  = (s.z * s.z + s.w * s.w) * inv;            // |psi1|^2
        float cr = (s.x * s.z + s.y * s.w) * inv;            // Re(psi0 * conj(psi1))
        float ci = (s.y * s.z - s.x * s.w) * inv;            // Im(psi0 * conj(psi1))
        float det = gg * q * q;                              // det(sigma_n)
        float E = entropy_from_det_f(det);                   // vne(sigma_n)
        acc0 += (double)t;
        acc1 += (double)(t * q);
        acc2 += (double)(t * cr);
        acc3 += (double)(t * ci);
        acc4 += (double)(t * E);
    }

    __shared__ double smem[BLOCK / 64][5];
    const int lane = threadIdx.x & 63, wave = threadIdx.x >> 6;
    double acc[5] = {acc0, acc1, acc2, acc3, acc4};
#pragma unroll
    for (int k = 0; k < 5; ++k) {
        double v = acc[k];
        for (int o = 32; o > 0; o >>= 1) v += __shfl_down(v, o, 64);
        if (lane == 0) smem[wave][k] = v;
    }
    __syncthreads();
    if (threadIdx.x == 0) {
#pragma unroll
        for (int k = 0; k < 5; ++k)
            partial[blockIdx.x * 5 + k] =
                smem[0][k] + smem[1][k] + smem[2][k] + smem[3][k];
    }
}

__global__ __launch_bounds__(BLOCK) void final_kernel(
    const double* __restrict__ partial, float* __restrict__ out)
{
    const int t = threadIdx.x;
    double v[5];
#pragma unroll
    for (int k = 0; k < 5; ++k)
        v[k] = partial[t * 5 + k] + partial[(t + BLOCK) * 5 + k];  // NBLK = 2*BLOCK

    __shared__ double smem[BLOCK / 64][5];
    const int lane = t & 63, wave = t >> 6;
#pragma unroll
    for (int k = 0; k < 5; ++k) {
        double x = v[k];
        for (int o = 32; o > 0; o >>= 1) x += __shfl_down(x, o, 64);
        if (lane == 0) smem[wave][k] = x;
    }
    __syncthreads();
    if (t == 0) {
        double T  = smem[0][0] + smem[1][0] + smem[2][0] + smem[3][0];
        double B  = smem[0][1] + smem[1][1] + smem[2][1] + smem[3][1];
        double Cr = smem[0][2] + smem[1][2] + smem[2][2] + smem[3][2];
        double Ci = smem[0][3] + smem[1][3] + smem[2][3] + smem[3][3];
        double D  = smem[0][4] + smem[1][4] + smem[2][4] + smem[3][4];

        const double b2 = G_NOISE;          // g
        const double a2 = 1.0 - G_NOISE;    // 1-g
        double r11 = B / T;                          // rho_11
        double r00 = 1.0 - r11;                      // trace(rho)=1 by construction
        double c2  = (Cr * Cr + Ci * Ci) / (T * T);  // |rho_01|^2
        // rho_out = [[r00+g*r11, a*rho01],[a*conj(rho01), (1-g)*r11]], trace 1
        double det = (r00 + b2 * r11) * (a2 * r11) - a2 * c2;
        double disc = 0.25 - det;
        disc = disc > 0.0 ? sqrt(disc) : 0.0;
        double lp = 0.5 + disc;
        double lm = lp > 0.0 ? det / lp : 0.0;
        double S_out = -(F_pade_d(lp) + F_pade_d(lm));
        double res = -S_out + D / T;                 // -(S(rho_out) - sum coeff*S(sigma))

        out[0] = (float)res;                         // reference output dtype: float
    }
}

extern "C" void kernel_launch(void* const* d_in, const int* in_sizes, int n_in,
                              void* d_out, int out_size, void* d_ws, size_t ws_size,
                              hipStream_t stream) {
    const float*  coeff = (const float*)d_in[0];
    const float4* state = (const float4*)d_in[1];   // 4 floats per sample, 16B aligned
    const int N = in_sizes[0];
    double* partial = (double*)d_ws;                // NBLK*5 doubles = 20480 B

    reduce_kernel<<<NBLK, BLOCK, 0, stream>>>(coeff, state, partial, N);
    final_kernel<<<1, BLOCK, 0, stream>>>(partial, (float*)d_out);
}